// Round 9
// baseline (296.659 us; speedup 1.0000x reference)
//
#include <hip/hip_runtime.h>
#include <cmath>

#define DEVI __device__ __forceinline__

DEVI float sigm(float x){ return 1.f/(1.f+expf(-x)); }

typedef __attribute__((ext_vector_type(8))) _Float16 half8;
typedef __attribute__((ext_vector_type(4))) _Float16 half4;
typedef __attribute__((ext_vector_type(4))) float float4v;

// ---------------- utility ----------------

__global__ void k_zero(float* __restrict__ p, int n){
  int i = blockIdx.x*256 + threadIdx.x;
  if (i < n) p[i] = 0.f;
}

// three fp32->fp16 casts in one launch (8 elems per thread)
__global__ void k_cast3(const float* __restrict__ a, _Float16* __restrict__ ah, int n1,
                        const float* __restrict__ b, _Float16* __restrict__ bh, int n2,
                        const float* __restrict__ c, _Float16* __restrict__ ch, int n3){
  int i = blockIdx.x*256 + threadIdx.x;
  const float* src; _Float16* dst; int off;
  if (i < n1){ src=a; dst=ah; off=i; }
  else if (i < n1+n2){ src=b; dst=bh; off=i-n1; }
  else if (i < n1+n2+n3){ src=c; dst=ch; off=i-n1-n2; }
  else return;
  const float* p = src + (size_t)off*8;
  half8 h;
  #pragma unroll
  for (int j = 0; j < 8; j++) h[j] = (_Float16)p[j];
  *(half8*)(dst + (size_t)off*8) = h;
}

// fused: column sums of memory (atomic into cm) + row-L2-normalized fp16 copy
__global__ __launch_bounds__(256) void k_prep_mem(const float* __restrict__ mem,
    float* __restrict__ cm, _Float16* __restrict__ mem_h){
  __shared__ float s2[4][128];
  int tid = threadIdx.x, wv = tid >> 6, lane = tid & 63;
  int n0 = blockIdx.x*64;                       // 32 blocks x 64 rows
  float c0 = 0.f, c1 = 0.f;
  for (int r = wv; r < 64; r += 4){
    const float* a = mem + (size_t)(n0+r)*128;
    float x0 = a[lane], x1 = a[lane+64];
    float ss = x0*x0 + x1*x1;
    #pragma unroll
    for (int o = 1; o < 64; o <<= 1) ss += __shfl_xor(ss, o);
    float invn = 1.f / fmaxf(sqrtf(ss), 1e-12f);
    mem_h[(size_t)(n0+r)*128 + lane]      = (_Float16)(x0*invn);
    mem_h[(size_t)(n0+r)*128 + 64 + lane] = (_Float16)(x1*invn);
    c0 += x0; c1 += x1;
  }
  s2[wv][lane] = c0; s2[wv][64+lane] = c1;
  __syncthreads();
  if (tid < 128) atomicAdd(&cm[tid], s2[0][tid]+s2[1][tid]+s2[2][tid]+s2[3][tid]);
}

// cin_h[b,k] = fp16( k<1024 ? x[b,k] : cm[(k-1024)%128]/2048 )
__global__ void k_cin(const float* __restrict__ x, const float* __restrict__ cm, _Float16* __restrict__ cin){
  int idx = blockIdx.x*256 + threadIdx.x;     // 256*1536
  int b = idx / 1536, k = idx - b*1536;
  float v = (k < 1024) ? x[b*1024 + k] : cm[(k-1024) & 127] * (1.f/2048.f);
  cin[idx] = (_Float16)v;
}

// ---------------- fp16 MFMA NT GEMM (proven R8): C = A @ B^T + bias1 + bias2 ----
#define QA 264
#define QB 520
__global__ __launch_bounds__(256) void gemm_f16(
    const _Float16* __restrict__ A, const _Float16* __restrict__ Bm, float* __restrict__ C,
    int M, int N, int K,
    const float* __restrict__ bias1, const float* __restrict__ bias2)
{
  __shared__ _Float16 Ah[2][8*QA];
  __shared__ _Float16 Bh[2][8*QB];
  const int tid = threadIdx.x;
  const int m0 = blockIdx.y*32, n0 = blockIdx.x*64;
  const int T = K >> 6;
  const int arow = tid >> 3, aq = tid & 7;
  const _Float16* Aptr = A + (size_t)(m0 + arow)*K + aq*8;
  const int brow = tid >> 3, bq = tid & 7;
  int nB0 = n0 + brow;      if (nB0 >= N) nB0 = N - 1;
  int nB1 = n0 + brow + 32; if (nB1 >= N) nB1 = N - 1;
  const _Float16* Bptr0 = Bm + (size_t)nB0*K + bq*8;
  const _Float16* Bptr1 = Bm + (size_t)nB1*K + bq*8;
  const int wA  = aq*QA + arow*8;
  const int wB0 = bq*QB + brow*8;
  const int wB1 = bq*QB + (brow+32)*8;
  const int wv_ = tid >> 6, lane = tid & 63;
  const int fq = lane >> 4, fr = lane & 15;
  const int m16 = (wv_ & 1)*16, nb = (wv_ >> 1)*32;

  half8 ra, rb0, rb1;
  ra  = *(const half8*)(Aptr);
  rb0 = *(const half8*)(Bptr0);
  rb1 = *(const half8*)(Bptr1);
  *(half8*)&Ah[0][wA]  = ra;
  *(half8*)&Bh[0][wB0] = rb0;
  *(half8*)&Bh[0][wB1] = rb1;
  __syncthreads();

  float4v acc0 = {0.f,0.f,0.f,0.f}, acc1 = {0.f,0.f,0.f,0.f};
  for (int t = 0; t < T; t++){
    const int cur = t & 1, nxt = cur ^ 1;
    if (t+1 < T){
      ra  = *(const half8*)(Aptr  + (t+1)*64);
      rb0 = *(const half8*)(Bptr0 + (t+1)*64);
      rb1 = *(const half8*)(Bptr1 + (t+1)*64);
    }
    #pragma unroll
    for (int s = 0; s < 2; s++){
      int q = s*4 + fq;
      half8 a  = *(half8*)&Ah[cur][q*QA + (m16+fr)*8];
      half8 b0 = *(half8*)&Bh[cur][q*QB + (nb+fr)*8];
      half8 b1 = *(half8*)&Bh[cur][q*QB + (nb+16+fr)*8];
      acc0 = __builtin_amdgcn_mfma_f32_16x16x32_f16(a, b0, acc0, 0, 0, 0);
      acc1 = __builtin_amdgcn_mfma_f32_16x16x32_f16(a, b1, acc1, 0, 0, 0);
    }
    if (t+1 < T){
      *(half8*)&Ah[nxt][wA]  = ra;
      *(half8*)&Bh[nxt][wB0] = rb0;
      *(half8*)&Bh[nxt][wB1] = rb1;
    }
    __syncthreads();
  }

  const int colA = n0 + nb + fr, colB = colA + 16;
  #pragma unroll
  for (int i = 0; i < 4; i++){
    int m = m0 + m16 + fq*4 + i;
    if (colA < N){
      float v = acc0[i];
      if (bias1) v += bias1[colA];
      if (bias2) v += bias2[colA];
      C[(size_t)m*N + colA] = v;
    }
    if (colB < N){
      float v = acc1[i];
      if (bias1) v += bias1[colB];
      if (bias2) v += bias2[colB];
      C[(size_t)m*N + colB] = v;
    }
  }
}

// LSTM gate activation -> fp16 h
__global__ void k_lstm(const float* __restrict__ g, _Float16* __restrict__ h){
  int idx = blockIdx.x*256 + threadIdx.x;    // 256*1024
  int b = idx >> 10, j = idx & 1023;
  const float* gr = g + (size_t)b*4096;
  float c = sigm(gr[j]) * tanhf(gr[2048 + j]);
  h[idx] = (_Float16)(sigm(gr[3072 + j]) * tanhf(c));
}

DEVI float blockReduce128(float v, float* lds2){
  #pragma unroll
  for (int o = 32; o > 0; o >>= 1) v += __shfl_xor(v, o);
  int w = threadIdx.x >> 6;
  __syncthreads();
  if ((threadIdx.x & 63) == 0) lds2[w] = v;
  __syncthreads();
  return lds2[0] + lds2[1];
}

// parse itf; wv_h has invwv folded, rks_h has invk*str folded
__global__ __launch_bounds__(128) void k_parse(const float* __restrict__ itf,
    _Float16* __restrict__ wv_h, float* __restrict__ ev, float* __restrict__ av,
    float* __restrict__ wg_, float* __restrict__ ag_,
    float* __restrict__ rm0, float* __restrict__ rm1, float* __restrict__ rm2,
    _Float16* __restrict__ rks_h)
{
  __shared__ float red[2];
  int b = blockIdx.x, t = threadIdx.x;
  const float* it = itf + (size_t)b*787;
  float wg = sigm(it[256]);
  float ag = sigm(it[257]);
  if (t == 0){ wg_[b] = wg; ag_[b] = ag; }
  float w = it[t];
  av[b*128 + t] = w * wg;
  ev[b*128 + t] = sigm(it[128 + t]) * wg;
  float ss = blockReduce128(w*w, red);
  float invwv = 1.f / fmaxf(sqrtf(ss), 1e-12f);
  wv_h[b*128 + t] = (_Float16)(w * invwv);
  if (t < 4){
    int rr = t;
    float m0v = it[259 + rr*3 + 0], m1v = it[259 + rr*3 + 1], m2v = it[259 + rr*3 + 2];
    float mx = fmaxf(m0v, fmaxf(m1v, m2v));
    float e0 = expf(m0v - mx), e1 = expf(m1v - mx), e2 = expf(m2v - mx);
    float inv = 1.f / (e0 + e1 + e2);
    rm0[b*4 + rr] = e0*inv; rm1[b*4 + rr] = e1*inv; rm2[b*4 + rr] = e2*inv;
  }
  #pragma unroll
  for (int rr = 0; rr < 4; rr++){
    float kv = it[275 + rr*128 + t];
    float ks = blockReduce128(kv*kv, red);
    float sx = it[271 + rr];
    float str = fmaxf(sx, 0.f) + log1pf(expf(-fabsf(sx)));
    float invk = 1.f / fmaxf(sqrtf(ks), 1e-12f);
    rks_h[((size_t)b*4 + rr)*128 + t] = (_Float16)(kv * invk * str);
  }
}

// allocation weighting, sort-free
__global__ __launch_bounds__(256) void k_alloc(const float* __restrict__ usage, float* __restrict__ out){
  __shared__ float red[4];
  int n = blockIdx.x, t = threadIdx.x;
  float un = usage[n];
  float prod = 1.f;
  #pragma unroll
  for (int i = 0; i < 8; i++){
    int m = t + i*256;
    float um = usage[m];
    bool before = (um < un) || (um == un && m < n);
    prod *= before ? (1.f - um) : 1.f;
  }
  #pragma unroll
  for (int o = 32; o > 0; o >>= 1) prod *= __shfl_xor(prod, o);
  if ((t & 63) == 0) red[t >> 6] = prod;
  __syncthreads();
  if (t == 0) out[n] = un * (red[0]*red[1]) * (red[2]*red[3]);
}

// softmax over 2048-wide rows, fused write-weighting epilogue:
// ww[b,n] = wg[b]*(0.5*softmax + 0.5*alloc[n]*ag[b])
__global__ __launch_bounds__(256) void k_softmax_ww(float* __restrict__ P,
    const float* __restrict__ alloc, const float* __restrict__ wg, const float* __restrict__ ag){
  __shared__ float red[4];
  float* p = P + (size_t)blockIdx.x*2048;
  int t = threadIdx.x;
  float r[8];
  float mx = -3.4e38f;
  #pragma unroll
  for (int i = 0; i < 8; i++){ r[i] = p[t + i*256]; mx = fmaxf(mx, r[i]); }
  #pragma unroll
  for (int o = 32; o > 0; o >>= 1) mx = fmaxf(mx, __shfl_xor(mx, o));
  if ((t & 63) == 0) red[t >> 6] = mx;
  __syncthreads();
  mx = fmaxf(fmaxf(red[0], red[1]), fmaxf(red[2], red[3]));
  float s = 0.f;
  #pragma unroll
  for (int i = 0; i < 8; i++){ r[i] = expf(r[i] - mx); s += r[i]; }
  #pragma unroll
  for (int o = 32; o > 0; o >>= 1) s += __shfl_xor(s, o);
  __syncthreads();
  if ((t & 63) == 0) red[t >> 6] = s;
  __syncthreads();
  s = red[0] + red[1] + red[2] + red[3];
  float inv = 1.f / s;
  float wgb = wg[blockIdx.x], agb = ag[blockIdx.x];
  #pragma unroll
  for (int i = 0; i < 8; i++){
    int col = t + i*256;
    p[col] = wgb*(0.5f*r[i]*inv + 0.5f*alloc[col]*agb);
  }
}

// fused row+col sums of link (2048x2048) in one pass; csl pre-zeroed (atomic)
__global__ __launch_bounds__(256) void k_linksums(const float* __restrict__ link,
    float* __restrict__ rsl, float* __restrict__ csl){
  __shared__ float rw[4][16];
  int tid = threadIdx.x, wv = tid >> 6, lane = tid & 63;
  int r0 = blockIdx.x*16;                       // 128 blocks x 16 rows
  int c0 = tid*8;
  float ca[8] = {0,0,0,0,0,0,0,0};
  for (int r = 0; r < 16; r++){
    const float* p = link + (size_t)(r0+r)*2048 + c0;
    float4 v0 = *(const float4*)p, v1 = *(const float4*)(p+4);
    ca[0]+=v0.x; ca[1]+=v0.y; ca[2]+=v0.z; ca[3]+=v0.w;
    ca[4]+=v1.x; ca[5]+=v1.y; ca[6]+=v1.z; ca[7]+=v1.w;
    float rp = v0.x+v0.y+v0.z+v0.w+v1.x+v1.y+v1.z+v1.w;
    #pragma unroll
    for (int o = 1; o < 64; o <<= 1) rp += __shfl_xor(rp, o);
    if (lane == 0) rw[wv][r] = rp;
  }
  __syncthreads();
  if (tid < 16) rsl[r0+tid] = rw[0][tid]+rw[1][tid]+rw[2][tid]+rw[3][tid];
  #pragma unroll
  for (int j = 0; j < 8; j++) atomicAdd(&csl[c0+j], ca[j]);
}

// generic row sums (wave per row) — used for tb = rowsum(ww)
__global__ void k_rowsum(const float* __restrict__ A, float* __restrict__ out, int rows, int cols){
  int w = (blockIdx.x*blockDim.x + threadIdx.x) >> 6;
  int lane = threadIdx.x & 63;
  if (w >= rows) return;
  const float* a = A + (size_t)w*cols;
  float s = 0.f;
  for (int c = lane; c < cols; c += 64) s += a[c];
  #pragma unroll
  for (int o = 32; o > 0; o >>= 1) s += __shfl_down(s, o);
  if (lane == 0) out[w] = s;
}

// bw/fw from link sums + lu sums
__global__ __launch_bounds__(1024) void k_bwfw(const float* __restrict__ ww, const float* __restrict__ tb,
                       const float* __restrict__ rowsum, const float* __restrict__ colsum,
                       float* __restrict__ bw, float* __restrict__ fw){
  __shared__ float sq[4][256], sd[4][256];
  int t = threadIdx.x & 255, z = threadIdx.x >> 8;
  int m = blockIdx.x*256 + t;
  float q = 0.f, dd = 0.f;
  for (int b = z*64; b < z*64 + 64; b++){
    float w = ww[(size_t)b*2048 + m];
    q  = fmaf(tb[b], w, q);
    dd = fmaf(w, w, dd);
  }
  sq[z][t] = q; sd[z][t] = dd;
  __syncthreads();
  if (z == 0){
    q  = sq[0][t] + sq[1][t] + sq[2][t] + sq[3][t];
    dd = sd[0][t] + sd[1][t] + sd[2][t] + sd[3][t];
    float lus = (q - dd) * (1.f/256.f);
    bw[m] = (0.9f*colsum[m] + 0.1f*lus) * (1.f/2048.f);
    fw[m] = (0.9f*rowsum[m] + 0.1f*lus) * (1.f/2048.f);
  }
}

// fused memory update: memn = mem*(1-ww^T@ev/B)+ww^T@av/B, emit fp16 normalized
// (memn_h) + fp16 raw (memnraw_h), and bwm/fwm partials (atomic, pre-zeroed).
// grid 64 blocks: 32 n-rows x 128 d (full rows), K=256 batch.
__global__ __launch_bounds__(256) void k_memupdate_fused(const float* __restrict__ ww,
    const float* __restrict__ ev, const float* __restrict__ av,
    const float* __restrict__ mem, const float* __restrict__ bw, const float* __restrict__ fw,
    _Float16* __restrict__ memn_h, _Float16* __restrict__ memnraw_h,
    float* __restrict__ bwm, float* __restrict__ fwm)
{
  __shared__ float Ws[16][34];
  __shared__ float Es[16][132], Vs[16][132];
  __shared__ float lb[128], lf[128];
  const int n0 = blockIdx.x*32;
  const int tid = threadIdx.x, tx = tid & 31, ty = tid >> 5;
  if (tid < 128){ lb[tid] = 0.f; lf[tid] = 0.f; }
  const int wk = tid >> 4, wn = (tid & 15)*2;
  const int ek = tid >> 4, ec = (tid & 15)*8;
  float ae[4][4] = {}, aa[4][4] = {};
  for (int k0 = 0; k0 < 256; k0 += 16){
    float2 vw  = *(const float2*)(ww + (size_t)(k0+wk)*2048 + n0 + wn);
    float4 ve0 = *(const float4*)(ev + (size_t)(k0+ek)*128 + ec);
    float4 ve1 = *(const float4*)(ev + (size_t)(k0+ek)*128 + ec + 4);
    float4 va0 = *(const float4*)(av + (size_t)(k0+ek)*128 + ec);
    float4 va1 = *(const float4*)(av + (size_t)(k0+ek)*128 + ec + 4);
    __syncthreads();
    Ws[wk][wn] = vw.x; Ws[wk][wn+1] = vw.y;
    *(float4*)&Es[ek][ec] = ve0; *(float4*)&Es[ek][ec+4] = ve1;
    *(float4*)&Vs[ek][ec] = va0; *(float4*)&Vs[ek][ec+4] = va1;
    __syncthreads();
    #pragma unroll
    for (int k = 0; k < 16; k++){
      float a[4], e[4], v[4];
      #pragma unroll
      for (int i = 0; i < 4; i++) a[i] = Ws[k][ty*4+i];
      #pragma unroll
      for (int j = 0; j < 4; j++){ e[j] = Es[k][tx*4+j]; v[j] = Vs[k][tx*4+j]; }
      #pragma unroll
      for (int i = 0; i < 4; i++)
        #pragma unroll
        for (int j = 0; j < 4; j++){
          ae[i][j] = fmaf(a[i], e[j], ae[i][j]);
          aa[i][j] = fmaf(a[i], v[j], aa[i][j]);
        }
    }
  }
  float ab[4] = {0,0,0,0}, af[4] = {0,0,0,0};
  #pragma unroll
  for (int i = 0; i < 4; i++){
    int n = n0 + ty*4 + i;
    float bwn = bw[n], fwn = fw[n];
    float v[4]; float ss = 0.f;
    #pragma unroll
    for (int j = 0; j < 4; j++){
      int d = tx*4 + j;
      float em = ae[i][j]*(1.f/256.f), am = aa[i][j]*(1.f/256.f);
      float mv = mem[(size_t)n*128 + d]*(1.f - em) + am;
      v[j] = mv; ss += mv*mv;
      ab[j] = fmaf(bwn, mv, ab[j]);
      af[j] = fmaf(fwn, mv, af[j]);
    }
    #pragma unroll
    for (int o = 1; o < 32; o <<= 1) ss += __shfl_xor(ss, o);
    float invn = 1.f / fmaxf(sqrtf(ss), 1e-12f);
    half4 hn, hr;
    #pragma unroll
    for (int j = 0; j < 4; j++){ hn[j] = (_Float16)(v[j]*invn); hr[j] = (_Float16)v[j]; }
    *(half4*)(memn_h    + (size_t)n*128 + tx*4) = hn;
    *(half4*)(memnraw_h + (size_t)n*128 + tx*4) = hr;
  }
  __syncthreads();
  #pragma unroll
  for (int j = 0; j < 4; j++){
    atomicAdd(&lb[tx*4+j], ab[j]);
    atomicAdd(&lf[tx*4+j], af[j]);
  }
  __syncthreads();
  if (tid < 128){
    atomicAdd(&bwm[tid], lb[tid]);
    atomicAdd(&fwm[tid], lf[tid]);
  }
}

// transpose memnraw_h (2048x128) -> memnT_h (128x2048)
__global__ __launch_bounds__(256) void k_transpose(const _Float16* __restrict__ src,
                                                   _Float16* __restrict__ dst){
  __shared__ _Float16 T[32][136];
  int tid = threadIdx.x;
  int k0 = blockIdx.x*32;                       // 64 blocks x 32 keys
  int rk = tid >> 3, cc = (tid & 7)*16;
  *(half8*)&T[rk][cc]   = *(const half8*)(src + (size_t)(k0+rk)*128 + cc);
  *(half8*)&T[rk][cc+8] = *(const half8*)(src + (size_t)(k0+rk)*128 + cc + 8);
  __syncthreads();
  int d = tid >> 1, kk = (tid & 1)*16;
  half8 o0, o1;
  #pragma unroll
  for (int j = 0; j < 8; j++){ o0[j] = T[kk+j][d]; o1[j] = T[kk+8+j][d]; }
  *(half8*)(dst + (size_t)d*2048 + k0 + kk)     = o0;
  *(half8*)(dst + (size_t)d*2048 + k0 + kk + 8) = o1;
}

// flash-style fused read addressing: per (16-q tile x 512-key chunk) block,
// QK^T -> online softmax -> PV, partials (m,l,acc) to global.
__global__ __launch_bounds__(256) void k_flash(
    const _Float16* __restrict__ Q, const _Float16* __restrict__ Kh,
    const _Float16* __restrict__ Vt,
    float* __restrict__ pacc, float* __restrict__ pm, float* __restrict__ pl)
{
  __shared__ _Float16 Pl[4][16][32];
  __shared__ float cmb[4][2080];      // per wave: m[16], l[16], acc[16*128]
  __shared__ float scl[4][16];
  const int tid = threadIdx.x;
  const int qt = blockIdx.x >> 2, kc = blockIdx.x & 3;
  const int wv = tid >> 6, lane = tid & 63;
  const int fq = lane >> 4, fr = lane & 15;
  const int kw0 = kc*512 + wv*128;

  half8 aq[4];
  #pragma unroll
  for (int c = 0; c < 4; c++)
    aq[c] = *(const half8*)(Q + (size_t)(qt*16 + fr)*128 + c*32 + fq*8);

  float m[4] = {-3.0e38f,-3.0e38f,-3.0e38f,-3.0e38f};
  float l[4] = {0.f,0.f,0.f,0.f};
  float4v acc[8] = {};
  for (int s = 0; s < 4; s++){
    const int kb = kw0 + s*32;
    float4v S0 = {0,0,0,0}, S1 = {0,0,0,0};
    #pragma unroll
    for (int c = 0; c < 4; c++){
      half8 b0 = *(const half8*)(Kh + (size_t)(kb + fr)*128      + c*32 + fq*8);
      half8 b1 = *(const half8*)(Kh + (size_t)(kb + 16 + fr)*128 + c*32 + fq*8);
      S0 = __builtin_amdgcn_mfma_f32_16x16x32_f16(aq[c], b0, S0, 0, 0, 0);
      S1 = __builtin_amdgcn_mfma_f32_16x16x32_f16(aq[c], b1, S1, 0, 0, 0);
    }
    float mt[4], ps[4];
    #pragma unroll
    for (int i = 0; i < 4; i++) mt[i] = fmaxf(S0[i], S1[i]);
    #pragma unroll
    for (int o = 1; o < 16; o <<= 1){
      #pragma unroll
      for (int i = 0; i < 4; i++) mt[i] = fmaxf(mt[i], __shfl_xor(mt[i], o));
    }
    #pragma unroll
    for (int i = 0; i < 4; i++){
      float mn = fmaxf(m[i], mt[i]);
      float al = expf(m[i] - mn);
      float p0 = expf(S0[i] - mn), p1 = expf(S1[i] - mn);
      S0[i] = p0; S1[i] = p1;
      ps[i] = p0 + p1;
      l[i] *= al;
      m[i] = mn;
      #pragma unroll
      for (int c = 0; c < 8; c++) acc[c][i] *= al;
    }
    #pragma unroll
    for (int o = 1; o < 16; o <<= 1){
      #pragma unroll
      for (int i = 0; i < 4; i++) ps[i] += __shfl_xor(ps[i], o);
    }
    #pragma unroll
    for (int i = 0; i < 4; i++) l[i] += ps[i];
    // P (C layout) -> LDS -> A-frag (wave-local; program order within wave)
    #pragma unroll
    for (int i = 0; i < 4; i++){
      Pl[wv][fq*4+i][fr]      = (_Float16)S0[i];
      Pl[wv][fq*4+i][16 + fr] = (_Float16)S1[i];
    }
    half8 pf = *(half8*)&Pl[wv][fr][fq*8];
    #pragma unroll
    for (int c = 0; c < 8; c++){
      half8 bv = *(const half8*)(Vt + (size_t)(c*16 + fr)*2048 + kb + fq*8);
      acc[c] = __builtin_amdgcn_mfma_f32_16x16x32_f16(pf, bv, acc[c], 0, 0, 0);
    }
  }
  // wave state -> LDS
  if (fr == 0){
    #pragma unroll
    for (int i = 0; i < 4; i++){
      cmb[wv][fq*4+i]      = m[i];
      cmb[wv][16 + fq*4+i] = l[i];
    }
  }
  #pragma unroll
  for (int c = 0; c < 8; c++)
    #pragma unroll
    for (int i = 0; i < 4; i++)
      cmb[wv][32 + (fq*4+i)*128 + c*16 + fr] = acc[c][i];
  __syncthreads();
  if (tid < 16){
    float mm = fmaxf(fmaxf(cmb[0][tid], cmb[1][tid]), fmaxf(cmb[2][tid], cmb[3][tid]));
    float ll = 0.f;
    #pragma unroll
    for (int w = 0; w < 4; w++){
      float e = expf(cmb[w][tid] - mm);
      scl[w][tid] = e;
      ll += e * cmb[w][16 + tid];
    }
    pm[blockIdx.x*16 + tid] = mm;
    pl[blockIdx.x*16 + tid] = ll;
  }
  __syncthreads();
  for (int e = tid; e < 2048; e += 256){
    int q = e >> 7;
    float a = scl[0][q]*cmb[0][32+e] + scl[1][q]*cmb[1][32+e]
            + scl[2][q]*cmb[2][32+e] + scl[3][q]*cmb[3][32+e];
    pacc[(size_t)blockIdx.x*2048 + e] = a;
  }
}

// combine 4 key-chunk partials + read-mode mix
__global__ void k_flashcomb(const float* __restrict__ pacc, const float* __restrict__ pm,
                            const float* __restrict__ pl,
                            const float* __restrict__ rm0, const float* __restrict__ rm1,
                            const float* __restrict__ rm2, const float* __restrict__ bwm,
                            const float* __restrict__ fwm, float* __restrict__ ro){
  int idx = blockIdx.x*256 + threadIdx.x;   // 131072
  int row = idx >> 7, d = idx & 127;
  int qt = row >> 4, q = row & 15;
  float mm = -3.0e38f;
  #pragma unroll
  for (int kc = 0; kc < 4; kc++) mm = fmaxf(mm, pm[(qt*4+kc)*16 + q]);
  float num = 0.f, den = 0.f;
  #pragma unroll
  for (int kc = 0; kc < 4; kc++){
    float e = expf(pm[(qt*4+kc)*16 + q] - mm);
    den += e * pl[(qt*4+kc)*16 + q];
    num += e * pacc[(size_t)(qt*4+kc)*2048 + q*128 + d];
  }
  float pv = num / den;
  ro[idx] = rm0[row]*pv + rm1[row]*bwm[d] + rm2[row]*fwm[d];
}

// hro = concat(h, read_out), fp16 out
__global__ void k_hro(const _Float16* __restrict__ h, const float* __restrict__ ro, _Float16* __restrict__ hro){
  int idx = blockIdx.x*256 + threadIdx.x;
  int b = idx / 1536, k = idx - b*1536;
  hro[idx] = (k < 1024) ? h[b*1024 + k] : (_Float16)ro[b*512 + k - 1024];
}

// ---------------- launcher ----------------

extern "C" void kernel_launch(void* const* d_in, const int* in_sizes, int n_in,
                              void* d_out, int out_size, void* d_ws, size_t ws_size,
                              hipStream_t stream)
{
  const float* x     = (const float*)d_in[0];
  const float* mem   = (const float*)d_in[1];
  const float* usage = (const float*)d_in[2];
  const float* link  = (const float*)d_in[3];
  const float* W_ih  = (const float*)d_in[4];
  // d_in[5] = W_hh: unused (h0 = 0)
  const float* b_ih  = (const float*)d_in[6];
  const float* b_hh  = (const float*)d_in[7];
  const float* W_if  = (const float*)d_in[8];
  const float* b_if  = (const float*)d_in[9];
  const float* W_out = (const float*)d_in[10];
  const float* b_out = (const float*)d_in[11];
  float* out = (float*)d_out;
  float* ws  = (float*)d_ws;

  // fp32 scratch
  float* cm     = ws + 0;         // 128  (zero region: cm,csl,bwm,fwm = 2432)
  float* csl    = ws + 128;       // 2048
  float* bwm    = ws + 2176;      // 128
  float* fwm    = ws + 2304;      // 128
  float* tb     = ws + 2432;      // 256
  float* bw     = ws + 2688;      // 2048
  float* fw     = ws + 4736;      // 2048
  float* wg     = ws + 6784;      // 256
  float* ag     = ws + 7040;      // 256
  float* rm0    = ws + 7296;      // 1024
  float* rm1    = ws + 8320;      // 1024
  float* rm2    = ws + 9344;      // 1024
  float* alloc  = ws + 10368;     // 2048
  float* rsl    = ws + 12416;     // 2048
  float* ev     = ws + 14464;     // 32768 (B x 128)
  float* av     = ws + 47232;     // 32768
  float* g      = ws + 80000;     // 1048576: LSTM gates, later flash partials
  float* itf    = ws + 1128576;   // 201472 (B x 787)
  float* ww     = ws + 1330048;   // 524288 (B x 2048)
  float* ro     = ws + 1854336;   // 131072 (B x R*D)
  // flash partials inside g (dead after k_lstm)
  float* pacc = g;                // 524288 (256 blocks x 2048)
  float* pm   = g + 524288;       // 4096
  float* pl   = g + 528384;       // 4096
  // fp16 scratch
  _Float16* Wih_h     = (_Float16*)(ws + 1985408);  // 6,291,456 h
  _Float16* Wif_h     = (_Float16*)(ws + 5131136);  //   805,888 h
  _Float16* Wout_h    = (_Float16*)(ws + 5534080);  // 1,572,864 h
  _Float16* cin_h     = (_Float16*)(ws + 6320512);  //   393,216 h
  _Float16* h_h       = (_Float16*)(ws + 6517120);  //   262,144 h
  _Float16* hro_h     = (_Float16*)(ws + 6648192);  //   393,216 h
  _Float16* wv_h      = (_Float16*)(ws + 6844800);  //    32,768 h
  _Float16* mem_h     = (_Float16*)(ws + 6861184);  //   262,144 h (row-normalized)
  _Float16* memn_h    = (_Float16*)(ws + 6992256);  //   262,144 h (row-normalized)
  _Float16* memnraw_h = (_Float16*)(ws + 7123328);  //   262,144 h (raw)
  _Float16* memnT_h   = (_Float16*)(ws + 7254400);  //   262,144 h (transposed raw)
  _Float16* rks_h     = (_Float16*)(ws + 7385472);  //   131,072 h
  // total ~7.45M floats = 29.8 MB

  // stage 0: zero accumulators; cast the three weight matrices to fp16
  k_zero <<<10, 256, 0, stream>>>(ws, 2432);
  k_cast3<<<4234, 256, 0, stream>>>(W_ih, Wih_h, 786432, W_if, Wif_h, 100736, W_out, Wout_h, 196608);

  // stage 1: controller input (colmean + rownorm fused)
  k_prep_mem<<<32, 256, 0, stream>>>(mem, cm, mem_h);
  k_cin     <<<1536, 256, 0, stream>>>(x, cm, cin_h);

  // stage 2: LSTM controller
  gemm_f16<<<dim3(64,8), 256, 0, stream>>>(cin_h, Wih_h, g, 256, 4096, 1536, b_ih, b_hh);
  k_lstm  <<<1024, 256, 0, stream>>>(g, h_h);

  // stage 3: interface
  gemm_f16<<<dim3(13,8), 256, 0, stream>>>(h_h, Wif_h, itf, 256, 787, 1024, b_if, nullptr);
  k_parse <<<256, 128, 0, stream>>>(itf, wv_h, ev, av, wg, ag, rm0, rm1, rm2, rks_h);

  // stage 4: write weighting (softmax + write-gates fused)
  k_alloc<<<2048, 256, 0, stream>>>(usage, alloc);
  gemm_f16<<<dim3(32,8), 256, 0, stream>>>(wv_h, mem_h, ww, 256, 2048, 128, nullptr, nullptr);
  k_softmax_ww<<<256, 256, 0, stream>>>(ww, alloc, wg, ag);

  // stage 5: link-derived read vectors (one pass over link)
  k_linksums<<<128, 256, 0, stream>>>(link, rsl, csl);
  k_rowsum  <<<64, 256, 0, stream>>>(ww, tb, 256, 2048);
  k_bwfw    <<<8, 1024, 0, stream>>>(ww, tb, rsl, csl, bw, fw);

  // stage 6: memory update (update + norms + fp16 emits + bwm/fwm fused)
  k_memupdate_fused<<<64, 256, 0, stream>>>(ww, ev, av, mem, bw, fw, memn_h, memnraw_h, bwm, fwm);
  k_transpose<<<64, 256, 0, stream>>>(memnraw_h, memnT_h);

  // stage 7: flash-fused read addressing (sim never materialized)
  k_flash    <<<256, 256, 0, stream>>>(rks_h, memn_h, memnT_h, pacc, pm, pl);
  k_flashcomb<<<512, 256, 0, stream>>>(pacc, pm, pl, rm0, rm1, rm2, bwm, fwm, ro);

  // stage 8: output projection
  k_hro   <<<1536, 256, 0, stream>>>(h_h, ro, hro_h);
  gemm_f16<<<dim3(16,8), 256, 0, stream>>>(hro_h, Wout_h, out, 256, 1024, 1536, b_out, nullptr);

  (void)in_sizes; (void)n_in; (void)out_size; (void)ws_size;
}

// Round 10
// 280.364 us; speedup vs baseline: 1.0581x; 1.0581x over previous
//
#include <hip/hip_runtime.h>
#include <cmath>

#define DEVI __device__ __forceinline__

DEVI float sigm(float x){ return 1.f/(1.f+expf(-x)); }

typedef __attribute__((ext_vector_type(8))) _Float16 half8;
typedef __attribute__((ext_vector_type(4))) _Float16 half4;
typedef __attribute__((ext_vector_type(4))) float float4v;

// ---------------- utility ----------------

__global__ void k_zero(float* __restrict__ p, int n){
  int i = blockIdx.x*256 + threadIdx.x;
  if (i < n) p[i] = 0.f;
}

// three fp32->fp16 casts in one launch (8 elems per thread)
__global__ void k_cast3(const float* __restrict__ a, _Float16* __restrict__ ah, int n1,
                        const float* __restrict__ b, _Float16* __restrict__ bh, int n2,
                        const float* __restrict__ c, _Float16* __restrict__ ch, int n3){
  int i = blockIdx.x*256 + threadIdx.x;
  const float* src; _Float16* dst; int off;
  if (i < n1){ src=a; dst=ah; off=i; }
  else if (i < n1+n2){ src=b; dst=bh; off=i-n1; }
  else if (i < n1+n2+n3){ src=c; dst=ch; off=i-n1-n2; }
  else return;
  const float* p = src + (size_t)off*8;
  half8 h;
  #pragma unroll
  for (int j = 0; j < 8; j++) h[j] = (_Float16)p[j];
  *(half8*)(dst + (size_t)off*8) = h;
}

// fused: column sums of memory (atomic into cm) + row-L2-normalized fp16 copy
__global__ __launch_bounds__(256) void k_prep_mem(const float* __restrict__ mem,
    float* __restrict__ cm, _Float16* __restrict__ mem_h){
  __shared__ float s2[4][128];
  int tid = threadIdx.x, wv = tid >> 6, lane = tid & 63;
  int n0 = blockIdx.x*64;                       // 32 blocks x 64 rows
  float c0 = 0.f, c1 = 0.f;
  for (int r = wv; r < 64; r += 4){
    const float* a = mem + (size_t)(n0+r)*128;
    float x0 = a[lane], x1 = a[lane+64];
    float ss = x0*x0 + x1*x1;
    #pragma unroll
    for (int o = 1; o < 64; o <<= 1) ss += __shfl_xor(ss, o);
    float invn = 1.f / fmaxf(sqrtf(ss), 1e-12f);
    mem_h[(size_t)(n0+r)*128 + lane]      = (_Float16)(x0*invn);
    mem_h[(size_t)(n0+r)*128 + 64 + lane] = (_Float16)(x1*invn);
    c0 += x0; c1 += x1;
  }
  s2[wv][lane] = c0; s2[wv][64+lane] = c1;
  __syncthreads();
  if (tid < 128) atomicAdd(&cm[tid], s2[0][tid]+s2[1][tid]+s2[2][tid]+s2[3][tid]);
}

// cin_h[b,k] = fp16( k<1024 ? x[b,k] : cm[(k-1024)%128]/2048 )
__global__ void k_cin(const float* __restrict__ x, const float* __restrict__ cm, _Float16* __restrict__ cin){
  int idx = blockIdx.x*256 + threadIdx.x;     // 256*1536
  int b = idx / 1536, k = idx - b*1536;
  float v = (k < 1024) ? x[b*1024 + k] : cm[(k-1024) & 127] * (1.f/2048.f);
  cin[idx] = (_Float16)v;
}

// ---------------- fp16 MFMA NT GEMM: C = A @ B^T + bias1 + bias2 ----------------
#define QA 264
#define QB 520
__global__ __launch_bounds__(256) void gemm_f16(
    const _Float16* __restrict__ A, const _Float16* __restrict__ Bm, float* __restrict__ C,
    int M, int N, int K,
    const float* __restrict__ bias1, const float* __restrict__ bias2)
{
  __shared__ _Float16 Ah[2][8*QA];
  __shared__ _Float16 Bh[2][8*QB];
  const int tid = threadIdx.x;
  const int m0 = blockIdx.y*32, n0 = blockIdx.x*64;
  const int T = K >> 6;
  const int arow = tid >> 3, aq = tid & 7;
  const _Float16* Aptr = A + (size_t)(m0 + arow)*K + aq*8;
  const int brow = tid >> 3, bq = tid & 7;
  int nB0 = n0 + brow;      if (nB0 >= N) nB0 = N - 1;
  int nB1 = n0 + brow + 32; if (nB1 >= N) nB1 = N - 1;
  const _Float16* Bptr0 = Bm + (size_t)nB0*K + bq*8;
  const _Float16* Bptr1 = Bm + (size_t)nB1*K + bq*8;
  const int wA  = aq*QA + arow*8;
  const int wB0 = bq*QB + brow*8;
  const int wB1 = bq*QB + (brow+32)*8;
  const int wv_ = tid >> 6, lane = tid & 63;
  const int fq = lane >> 4, fr = lane & 15;
  const int m16 = (wv_ & 1)*16, nb = (wv_ >> 1)*32;

  half8 ra, rb0, rb1;
  ra  = *(const half8*)(Aptr);
  rb0 = *(const half8*)(Bptr0);
  rb1 = *(const half8*)(Bptr1);
  *(half8*)&Ah[0][wA]  = ra;
  *(half8*)&Bh[0][wB0] = rb0;
  *(half8*)&Bh[0][wB1] = rb1;
  __syncthreads();

  float4v acc0 = {0.f,0.f,0.f,0.f}, acc1 = {0.f,0.f,0.f,0.f};
  for (int t = 0; t < T; t++){
    const int cur = t & 1, nxt = cur ^ 1;
    if (t+1 < T){
      ra  = *(const half8*)(Aptr  + (t+1)*64);
      rb0 = *(const half8*)(Bptr0 + (t+1)*64);
      rb1 = *(const half8*)(Bptr1 + (t+1)*64);
    }
    #pragma unroll
    for (int s = 0; s < 2; s++){
      int q = s*4 + fq;
      half8 a  = *(half8*)&Ah[cur][q*QA + (m16+fr)*8];
      half8 b0 = *(half8*)&Bh[cur][q*QB + (nb+fr)*8];
      half8 b1 = *(half8*)&Bh[cur][q*QB + (nb+16+fr)*8];
      acc0 = __builtin_amdgcn_mfma_f32_16x16x32_f16(a, b0, acc0, 0, 0, 0);
      acc1 = __builtin_amdgcn_mfma_f32_16x16x32_f16(a, b1, acc1, 0, 0, 0);
    }
    if (t+1 < T){
      *(half8*)&Ah[nxt][wA]  = ra;
      *(half8*)&Bh[nxt][wB0] = rb0;
      *(half8*)&Bh[nxt][wB1] = rb1;
    }
    __syncthreads();
  }

  const int colA = n0 + nb + fr, colB = colA + 16;
  #pragma unroll
  for (int i = 0; i < 4; i++){
    int m = m0 + m16 + fq*4 + i;
    if (colA < N){
      float v = acc0[i];
      if (bias1) v += bias1[colA];
      if (bias2) v += bias2[colA];
      C[(size_t)m*N + colA] = v;
    }
    if (colB < N){
      float v = acc1[i];
      if (bias1) v += bias1[colB];
      if (bias2) v += bias2[colB];
      C[(size_t)m*N + colB] = v;
    }
  }
}

// LSTM gate activation -> fp16 h
__global__ void k_lstm(const float* __restrict__ g, _Float16* __restrict__ h){
  int idx = blockIdx.x*256 + threadIdx.x;    // 256*1024
  int b = idx >> 10, j = idx & 1023;
  const float* gr = g + (size_t)b*4096;
  float c = sigm(gr[j]) * tanhf(gr[2048 + j]);
  h[idx] = (_Float16)(sigm(gr[3072 + j]) * tanhf(c));
}

DEVI float blockReduce128(float v, float* lds2){
  #pragma unroll
  for (int o = 32; o > 0; o >>= 1) v += __shfl_xor(v, o);
  int w = threadIdx.x >> 6;
  __syncthreads();
  if ((threadIdx.x & 63) == 0) lds2[w] = v;
  __syncthreads();
  return lds2[0] + lds2[1];
}

// parse itf; wv_h has invwv folded, rks_h has invk*str folded
__global__ __launch_bounds__(128) void k_parse(const float* __restrict__ itf,
    _Float16* __restrict__ wv_h, float* __restrict__ ev, float* __restrict__ av,
    float* __restrict__ wg_, float* __restrict__ ag_,
    float* __restrict__ rm0, float* __restrict__ rm1, float* __restrict__ rm2,
    _Float16* __restrict__ rks_h)
{
  __shared__ float red[2];
  int b = blockIdx.x, t = threadIdx.x;
  const float* it = itf + (size_t)b*787;
  float wg = sigm(it[256]);
  float ag = sigm(it[257]);
  if (t == 0){ wg_[b] = wg; ag_[b] = ag; }
  float w = it[t];
  av[b*128 + t] = w * wg;
  ev[b*128 + t] = sigm(it[128 + t]) * wg;
  float ss = blockReduce128(w*w, red);
  float invwv = 1.f / fmaxf(sqrtf(ss), 1e-12f);
  wv_h[b*128 + t] = (_Float16)(w * invwv);
  if (t < 4){
    int rr = t;
    float m0v = it[259 + rr*3 + 0], m1v = it[259 + rr*3 + 1], m2v = it[259 + rr*3 + 2];
    float mx = fmaxf(m0v, fmaxf(m1v, m2v));
    float e0 = expf(m0v - mx), e1 = expf(m1v - mx), e2 = expf(m2v - mx);
    float inv = 1.f / (e0 + e1 + e2);
    rm0[b*4 + rr] = e0*inv; rm1[b*4 + rr] = e1*inv; rm2[b*4 + rr] = e2*inv;
  }
  #pragma unroll
  for (int rr = 0; rr < 4; rr++){
    float kv = it[275 + rr*128 + t];
    float ks = blockReduce128(kv*kv, red);
    float sx = it[271 + rr];
    float str = fmaxf(sx, 0.f) + log1pf(expf(-fabsf(sx)));
    float invk = 1.f / fmaxf(sqrtf(ks), 1e-12f);
    rks_h[((size_t)b*4 + rr)*128 + t] = (_Float16)(kv * invk * str);
  }
}

// allocation weighting, sort-free
__global__ __launch_bounds__(256) void k_alloc(const float* __restrict__ usage, float* __restrict__ out){
  __shared__ float red[4];
  int n = blockIdx.x, t = threadIdx.x;
  float un = usage[n];
  float prod = 1.f;
  #pragma unroll
  for (int i = 0; i < 8; i++){
    int m = t + i*256;
    float um = usage[m];
    bool before = (um < un) || (um == un && m < n);
    prod *= before ? (1.f - um) : 1.f;
  }
  #pragma unroll
  for (int o = 32; o > 0; o >>= 1) prod *= __shfl_xor(prod, o);
  if ((t & 63) == 0) red[t >> 6] = prod;
  __syncthreads();
  if (t == 0) out[n] = un * (red[0]*red[1]) * (red[2]*red[3]);
}

// softmax over 2048-wide rows, fused write-weighting epilogue
__global__ __launch_bounds__(256) void k_softmax_ww(float* __restrict__ P,
    const float* __restrict__ alloc, const float* __restrict__ wg, const float* __restrict__ ag){
  __shared__ float red[4];
  float* p = P + (size_t)blockIdx.x*2048;
  int t = threadIdx.x;
  float r[8];
  float mx = -3.4e38f;
  #pragma unroll
  for (int i = 0; i < 8; i++){ r[i] = p[t + i*256]; mx = fmaxf(mx, r[i]); }
  #pragma unroll
  for (int o = 32; o > 0; o >>= 1) mx = fmaxf(mx, __shfl_xor(mx, o));
  if ((t & 63) == 0) red[t >> 6] = mx;
  __syncthreads();
  mx = fmaxf(fmaxf(red[0], red[1]), fmaxf(red[2], red[3]));
  float s = 0.f;
  #pragma unroll
  for (int i = 0; i < 8; i++){ r[i] = expf(r[i] - mx); s += r[i]; }
  #pragma unroll
  for (int o = 32; o > 0; o >>= 1) s += __shfl_xor(s, o);
  __syncthreads();
  if ((t & 63) == 0) red[t >> 6] = s;
  __syncthreads();
  s = red[0] + red[1] + red[2] + red[3];
  float inv = 1.f / s;
  float wgb = wg[blockIdx.x], agb = ag[blockIdx.x];
  #pragma unroll
  for (int i = 0; i < 8; i++){
    int col = t + i*256;
    p[col] = wgb*(0.5f*r[i]*inv + 0.5f*alloc[col]*agb);
  }
}

// generic row sums (wave per row) — link rows and tb = rowsum(ww)
__global__ void k_rowsum(const float* __restrict__ A, float* __restrict__ out, int rows, int cols){
  int w = (blockIdx.x*blockDim.x + threadIdx.x) >> 6;
  int lane = threadIdx.x & 63;
  if (w >= rows) return;
  const float* a = A + (size_t)w*cols;
  float s = 0.f;
  for (int c = lane; c < cols; c += 64) s += a[c];
  #pragma unroll
  for (int o = 32; o > 0; o >>= 1) s += __shfl_down(s, o);
  if (lane == 0) out[w] = s;
}

// column sums of a (2048 x 2048) matrix (out pre-zeroed, 16-way atomic)
__global__ void k_colsum2048(const float* __restrict__ A, float* __restrict__ out){
  int c = blockIdx.x*256 + threadIdx.x;
  int r0 = blockIdx.y*128;
  float s = 0.f;
  for (int rr = 0; rr < 128; rr++) s += A[(size_t)(r0+rr)*2048 + c];
  atomicAdd(&out[c], s);
}

// bw/fw from link sums + lu sums
__global__ __launch_bounds__(1024) void k_bwfw(const float* __restrict__ ww, const float* __restrict__ tb,
                       const float* __restrict__ rowsum, const float* __restrict__ colsum,
                       float* __restrict__ bw, float* __restrict__ fw){
  __shared__ float sq[4][256], sd[4][256];
  int t = threadIdx.x & 255, z = threadIdx.x >> 8;
  int m = blockIdx.x*256 + t;
  float q = 0.f, dd = 0.f;
  for (int b = z*64; b < z*64 + 64; b++){
    float w = ww[(size_t)b*2048 + m];
    q  = fmaf(tb[b], w, q);
    dd = fmaf(w, w, dd);
  }
  sq[z][t] = q; sd[z][t] = dd;
  __syncthreads();
  if (z == 0){
    q  = sq[0][t] + sq[1][t] + sq[2][t] + sq[3][t];
    dd = sd[0][t] + sd[1][t] + sd[2][t] + sd[3][t];
    float lus = (q - dd) * (1.f/256.f);
    bw[m] = (0.9f*colsum[m] + 0.1f*lus) * (1.f/2048.f);
    fw[m] = (0.9f*rowsum[m] + 0.1f*lus) * (1.f/2048.f);
  }
}

// fused memory update: memn = mem*(1-ww^T@ev/B)+ww^T@av/B, emit fp16 normalized
// (memn_h) + fp16 raw (memnraw_h), and bwm/fwm partials (atomic, pre-zeroed).
__global__ __launch_bounds__(256) void k_memupdate_fused(const float* __restrict__ ww,
    const float* __restrict__ ev, const float* __restrict__ av,
    const float* __restrict__ mem, const float* __restrict__ bw, const float* __restrict__ fw,
    _Float16* __restrict__ memn_h, _Float16* __restrict__ memnraw_h,
    float* __restrict__ bwm, float* __restrict__ fwm)
{
  __shared__ float Ws[16][34];
  __shared__ float Es[16][132], Vs[16][132];
  __shared__ float lb[128], lf[128];
  const int n0 = blockIdx.x*32;
  const int tid = threadIdx.x, tx = tid & 31, ty = tid >> 5;
  if (tid < 128){ lb[tid] = 0.f; lf[tid] = 0.f; }
  const int wk = tid >> 4, wn = (tid & 15)*2;
  const int ek = tid >> 4, ec = (tid & 15)*8;
  float ae[4][4] = {}, aa[4][4] = {};
  for (int k0 = 0; k0 < 256; k0 += 16){
    float2 vw  = *(const float2*)(ww + (size_t)(k0+wk)*2048 + n0 + wn);
    float4 ve0 = *(const float4*)(ev + (size_t)(k0+ek)*128 + ec);
    float4 ve1 = *(const float4*)(ev + (size_t)(k0+ek)*128 + ec + 4);
    float4 va0 = *(const float4*)(av + (size_t)(k0+ek)*128 + ec);
    float4 va1 = *(const float4*)(av + (size_t)(k0+ek)*128 + ec + 4);
    __syncthreads();
    Ws[wk][wn] = vw.x; Ws[wk][wn+1] = vw.y;
    *(float4*)&Es[ek][ec] = ve0; *(float4*)&Es[ek][ec+4] = ve1;
    *(float4*)&Vs[ek][ec] = va0; *(float4*)&Vs[ek][ec+4] = va1;
    __syncthreads();
    #pragma unroll
    for (int k = 0; k < 16; k++){
      float a[4], e[4], v[4];
      #pragma unroll
      for (int i = 0; i < 4; i++) a[i] = Ws[k][ty*4+i];
      #pragma unroll
      for (int j = 0; j < 4; j++){ e[j] = Es[k][tx*4+j]; v[j] = Vs[k][tx*4+j]; }
      #pragma unroll
      for (int i = 0; i < 4; i++)
        #pragma unroll
        for (int j = 0; j < 4; j++){
          ae[i][j] = fmaf(a[i], e[j], ae[i][j]);
          aa[i][j] = fmaf(a[i], v[j], aa[i][j]);
        }
    }
  }
  float ab[4] = {0,0,0,0}, af[4] = {0,0,0,0};
  #pragma unroll
  for (int i = 0; i < 4; i++){
    int n = n0 + ty*4 + i;
    float bwn = bw[n], fwn = fw[n];
    float v[4]; float ss = 0.f;
    #pragma unroll
    for (int j = 0; j < 4; j++){
      int d = tx*4 + j;
      float em = ae[i][j]*(1.f/256.f), am = aa[i][j]*(1.f/256.f);
      float mv = mem[(size_t)n*128 + d]*(1.f - em) + am;
      v[j] = mv; ss += mv*mv;
      ab[j] = fmaf(bwn, mv, ab[j]);
      af[j] = fmaf(fwn, mv, af[j]);
    }
    #pragma unroll
    for (int o = 1; o < 32; o <<= 1) ss += __shfl_xor(ss, o);
    float invn = 1.f / fmaxf(sqrtf(ss), 1e-12f);
    half4 hn, hr;
    #pragma unroll
    for (int j = 0; j < 4; j++){ hn[j] = (_Float16)(v[j]*invn); hr[j] = (_Float16)v[j]; }
    *(half4*)(memn_h    + (size_t)n*128 + tx*4) = hn;
    *(half4*)(memnraw_h + (size_t)n*128 + tx*4) = hr;
  }
  __syncthreads();
  #pragma unroll
  for (int j = 0; j < 4; j++){
    atomicAdd(&lb[tx*4+j], ab[j]);
    atomicAdd(&lf[tx*4+j], af[j]);
  }
  __syncthreads();
  if (tid < 128){
    atomicAdd(&bwm[tid], lb[tid]);
    atomicAdd(&fwm[tid], lf[tid]);
  }
}

// transpose memnraw_h (2048x128) -> memnT_h (128x2048)
__global__ __launch_bounds__(256) void k_transpose(const _Float16* __restrict__ src,
                                                   _Float16* __restrict__ dst){
  __shared__ _Float16 T[32][136];
  int tid = threadIdx.x;
  int k0 = blockIdx.x*32;                       // 64 blocks x 32 keys
  int rk = tid >> 3, cc = (tid & 7)*16;
  *(half8*)&T[rk][cc]   = *(const half8*)(src + (size_t)(k0+rk)*128 + cc);
  *(half8*)&T[rk][cc+8] = *(const half8*)(src + (size_t)(k0+rk)*128 + cc + 8);
  __syncthreads();
  int d = tid >> 1, kk = (tid & 1)*16;
  half8 o0, o1;
  #pragma unroll
  for (int j = 0; j < 8; j++){ o0[j] = T[kk+j][d]; o1[j] = T[kk+8+j][d]; }
  *(half8*)(dst + (size_t)d*2048 + k0 + kk)     = o0;
  *(half8*)(dst + (size_t)d*2048 + k0 + kk + 8) = o1;
}

// flash-style fused read addressing
__global__ __launch_bounds__(256) void k_flash(
    const _Float16* __restrict__ Q, const _Float16* __restrict__ Kh,
    const _Float16* __restrict__ Vt,
    float* __restrict__ pacc, float* __restrict__ pm, float* __restrict__ pl)
{
  __shared__ _Float16 Pl[4][16][32];
  __shared__ float cmb[4][2080];
  __shared__ float scl[4][16];
  const int tid = threadIdx.x;
  const int qt = blockIdx.x >> 2, kc = blockIdx.x & 3;
  const int wv = tid >> 6, lane = tid & 63;
  const int fq = lane >> 4, fr = lane & 15;
  const int kw0 = kc*512 + wv*128;

  half8 aq[4];
  #pragma unroll
  for (int c = 0; c < 4; c++)
    aq[c] = *(const half8*)(Q + (size_t)(qt*16 + fr)*128 + c*32 + fq*8);

  float m[4] = {-3.0e38f,-3.0e38f,-3.0e38f,-3.0e38f};
  float l[4] = {0.f,0.f,0.f,0.f};
  float4v acc[8] = {};
  for (int s = 0; s < 4; s++){
    const int kb = kw0 + s*32;
    float4v S0 = {0,0,0,0}, S1 = {0,0,0,0};
    #pragma unroll
    for (int c = 0; c < 4; c++){
      half8 b0 = *(const half8*)(Kh + (size_t)(kb + fr)*128      + c*32 + fq*8);
      half8 b1 = *(const half8*)(Kh + (size_t)(kb + 16 + fr)*128 + c*32 + fq*8);
      S0 = __builtin_amdgcn_mfma_f32_16x16x32_f16(aq[c], b0, S0, 0, 0, 0);
      S1 = __builtin_amdgcn_mfma_f32_16x16x32_f16(aq[c], b1, S1, 0, 0, 0);
    }
    float mt[4], ps[4];
    #pragma unroll
    for (int i = 0; i < 4; i++) mt[i] = fmaxf(S0[i], S1[i]);
    #pragma unroll
    for (int o = 1; o < 16; o <<= 1){
      #pragma unroll
      for (int i = 0; i < 4; i++) mt[i] = fmaxf(mt[i], __shfl_xor(mt[i], o));
    }
    #pragma unroll
    for (int i = 0; i < 4; i++){
      float mn = fmaxf(m[i], mt[i]);
      float al = expf(m[i] - mn);
      float p0 = expf(S0[i] - mn), p1 = expf(S1[i] - mn);
      S0[i] = p0; S1[i] = p1;
      ps[i] = p0 + p1;
      l[i] *= al;
      m[i] = mn;
      #pragma unroll
      for (int c = 0; c < 8; c++) acc[c][i] *= al;
    }
    #pragma unroll
    for (int o = 1; o < 16; o <<= 1){
      #pragma unroll
      for (int i = 0; i < 4; i++) ps[i] += __shfl_xor(ps[i], o);
    }
    #pragma unroll
    for (int i = 0; i < 4; i++) l[i] += ps[i];
    #pragma unroll
    for (int i = 0; i < 4; i++){
      Pl[wv][fq*4+i][fr]      = (_Float16)S0[i];
      Pl[wv][fq*4+i][16 + fr] = (_Float16)S1[i];
    }
    half8 pf = *(half8*)&Pl[wv][fr][fq*8];
    #pragma unroll
    for (int c = 0; c < 8; c++){
      half8 bv = *(const half8*)(Vt + (size_t)(c*16 + fr)*2048 + kb + fq*8);
      acc[c] = __builtin_amdgcn_mfma_f32_16x16x32_f16(pf, bv, acc[c], 0, 0, 0);
    }
  }
  if (fr == 0){
    #pragma unroll
    for (int i = 0; i < 4; i++){
      cmb[wv][fq*4+i]      = m[i];
      cmb[wv][16 + fq*4+i] = l[i];
    }
  }
  #pragma unroll
  for (int c = 0; c < 8; c++)
    #pragma unroll
    for (int i = 0; i < 4; i++)
      cmb[wv][32 + (fq*4+i)*128 + c*16 + fr] = acc[c][i];
  __syncthreads();
  if (tid < 16){
    float mm = fmaxf(fmaxf(cmb[0][tid], cmb[1][tid]), fmaxf(cmb[2][tid], cmb[3][tid]));
    float ll = 0.f;
    #pragma unroll
    for (int w = 0; w < 4; w++){
      float e = expf(cmb[w][tid] - mm);
      scl[w][tid] = e;
      ll += e * cmb[w][16 + tid];
    }
    pm[blockIdx.x*16 + tid] = mm;
    pl[blockIdx.x*16 + tid] = ll;
  }
  __syncthreads();
  for (int e = tid; e < 2048; e += 256){
    int q = e >> 7;
    float a = scl[0][q]*cmb[0][32+e] + scl[1][q]*cmb[1][32+e]
            + scl[2][q]*cmb[2][32+e] + scl[3][q]*cmb[3][32+e];
    pacc[(size_t)blockIdx.x*2048 + e] = a;
  }
}

// combine 4 key-chunk partials + read-mode mix
__global__ void k_flashcomb(const float* __restrict__ pacc, const float* __restrict__ pm,
                            const float* __restrict__ pl,
                            const float* __restrict__ rm0, const float* __restrict__ rm1,
                            const float* __restrict__ rm2, const float* __restrict__ bwm,
                            const float* __restrict__ fwm, float* __restrict__ ro){
  int idx = blockIdx.x*256 + threadIdx.x;   // 131072
  int row = idx >> 7, d = idx & 127;
  int qt = row >> 4, q = row & 15;
  float mm = -3.0e38f;
  #pragma unroll
  for (int kc = 0; kc < 4; kc++) mm = fmaxf(mm, pm[(qt*4+kc)*16 + q]);
  float num = 0.f, den = 0.f;
  #pragma unroll
  for (int kc = 0; kc < 4; kc++){
    float e = expf(pm[(qt*4+kc)*16 + q] - mm);
    den += e * pl[(qt*4+kc)*16 + q];
    num += e * pacc[(size_t)(qt*4+kc)*2048 + q*128 + d];
  }
  float pv = num / den;
  ro[idx] = rm0[row]*pv + rm1[row]*bwm[d] + rm2[row]*fwm[d];
}

// hro = concat(h, read_out), fp16 out
__global__ void k_hro(const _Float16* __restrict__ h, const float* __restrict__ ro, _Float16* __restrict__ hro){
  int idx = blockIdx.x*256 + threadIdx.x;
  int b = idx / 1536, k = idx - b*1536;
  hro[idx] = (k < 1024) ? h[b*1024 + k] : (_Float16)ro[b*512 + k - 1024];
}

// ---------------- launcher ----------------

extern "C" void kernel_launch(void* const* d_in, const int* in_sizes, int n_in,
                              void* d_out, int out_size, void* d_ws, size_t ws_size,
                              hipStream_t stream)
{
  const float* x     = (const float*)d_in[0];
  const float* mem   = (const float*)d_in[1];
  const float* usage = (const float*)d_in[2];
  const float* link  = (const float*)d_in[3];
  const float* W_ih  = (const float*)d_in[4];
  // d_in[5] = W_hh: unused (h0 = 0)
  const float* b_ih  = (const float*)d_in[6];
  const float* b_hh  = (const float*)d_in[7];
  const float* W_if  = (const float*)d_in[8];
  const float* b_if  = (const float*)d_in[9];
  const float* W_out = (const float*)d_in[10];
  const float* b_out = (const float*)d_in[11];
  float* out = (float*)d_out;
  float* ws  = (float*)d_ws;

  // fp32 scratch
  float* cm     = ws + 0;         // 128  (zero region: cm,csl,bwm,fwm = 2432)
  float* csl    = ws + 128;       // 2048
  float* bwm    = ws + 2176;      // 128
  float* fwm    = ws + 2304;      // 128
  float* tb     = ws + 2432;      // 256
  float* bw     = ws + 2688;      // 2048
  float* fw     = ws + 4736;      // 2048
  float* wg     = ws + 6784;      // 256
  float* ag     = ws + 7040;      // 256
  float* rm0    = ws + 7296;      // 1024
  float* rm1    = ws + 8320;      // 1024
  float* rm2    = ws + 9344;      // 1024
  float* alloc  = ws + 10368;     // 2048
  float* rsl    = ws + 12416;     // 2048
  float* ev     = ws + 14464;     // 32768 (B x 128)
  float* av     = ws + 47232;     // 32768
  float* g      = ws + 80000;     // 1048576: LSTM gates, later flash partials
  float* itf    = ws + 1128576;   // 201472 (B x 787)
  float* ww     = ws + 1330048;   // 524288 (B x 2048)
  float* ro     = ws + 1854336;   // 131072 (B x R*D)
  // flash partials inside g (dead after k_lstm)
  float* pacc = g;                // 524288 (256 blocks x 2048)
  float* pm   = g + 524288;       // 4096
  float* pl   = g + 528384;       // 4096
  // fp16 scratch
  _Float16* Wih_h     = (_Float16*)(ws + 1985408);  // 6,291,456 h
  _Float16* Wif_h     = (_Float16*)(ws + 5131136);  //   805,888 h
  _Float16* Wout_h    = (_Float16*)(ws + 5534080);  // 1,572,864 h
  _Float16* cin_h     = (_Float16*)(ws + 6320512);  //   393,216 h
  _Float16* h_h       = (_Float16*)(ws + 6517120);  //   262,144 h
  _Float16* hro_h     = (_Float16*)(ws + 6648192);  //   393,216 h
  _Float16* wv_h      = (_Float16*)(ws + 6844800);  //    32,768 h
  _Float16* mem_h     = (_Float16*)(ws + 6861184);  //   262,144 h (row-normalized)
  _Float16* memn_h    = (_Float16*)(ws + 6992256);  //   262,144 h (row-normalized)
  _Float16* memnraw_h = (_Float16*)(ws + 7123328);  //   262,144 h (raw)
  _Float16* memnT_h   = (_Float16*)(ws + 7254400);  //   262,144 h (transposed raw)
  _Float16* rks_h     = (_Float16*)(ws + 7385472);  //   131,072 h
  // total ~7.45M floats = 29.8 MB

  // stage 0: zero accumulators; cast the three weight matrices to fp16
  k_zero <<<10, 256, 0, stream>>>(ws, 2432);
  k_cast3<<<4234, 256, 0, stream>>>(W_ih, Wih_h, 786432, W_if, Wif_h, 100736, W_out, Wout_h, 196608);

  // stage 1: controller input (colmean + rownorm fused)
  k_prep_mem<<<32, 256, 0, stream>>>(mem, cm, mem_h);
  k_cin     <<<1536, 256, 0, stream>>>(x, cm, cin_h);

  // stage 2: LSTM controller
  gemm_f16<<<dim3(64,8), 256, 0, stream>>>(cin_h, Wih_h, g, 256, 4096, 1536, b_ih, b_hh);
  k_lstm  <<<1024, 256, 0, stream>>>(g, h_h);

  // stage 3: interface
  gemm_f16<<<dim3(13,8), 256, 0, stream>>>(h_h, Wif_h, itf, 256, 787, 1024, b_if, nullptr);
  k_parse <<<256, 128, 0, stream>>>(itf, wv_h, ev, av, wg, ag, rm0, rm1, rm2, rks_h);

  // stage 4: write weighting (softmax + write-gates fused)
  k_alloc<<<2048, 256, 0, stream>>>(usage, alloc);
  gemm_f16<<<dim3(32,8), 256, 0, stream>>>(wv_h, mem_h, ww, 256, 2048, 128, nullptr, nullptr);
  k_softmax_ww<<<256, 256, 0, stream>>>(ww, alloc, wg, ag);

  // stage 5: link-derived read vectors (separate high-occupancy passes — the
  // R9 single-pass fusion was latency-bound at 128 blocks: 44 us vs ~10 here)
  k_rowsum<<<512, 256, 0, stream>>>(link, rsl, 2048, 2048);
  k_colsum2048<<<dim3(8,16), 256, 0, stream>>>(link, csl);
  k_rowsum<<<64, 256, 0, stream>>>(ww, tb, 256, 2048);
  k_bwfw  <<<8, 1024, 0, stream>>>(ww, tb, rsl, csl, bw, fw);

  // stage 6: memory update (update + norms + fp16 emits + bwm/fwm fused)
  k_memupdate_fused<<<64, 256, 0, stream>>>(ww, ev, av, mem, bw, fw, memn_h, memnraw_h, bwm, fwm);
  k_transpose<<<64, 256, 0, stream>>>(memnraw_h, memnT_h);

  // stage 7: flash-fused read addressing (sim never materialized)
  k_flash    <<<256, 256, 0, stream>>>(rks_h, memn_h, memnT_h, pacc, pm, pl);
  k_flashcomb<<<512, 256, 0, stream>>>(pacc, pm, pl, rm0, rm1, rm2, bwm, fwm, ro);

  // stage 8: output projection
  k_hro   <<<1536, 256, 0, stream>>>(h_h, ro, hro_h);
  gemm_f16<<<dim3(16,8), 256, 0, stream>>>(hro_h, Wout_h, out, 256, 1024, 1536, b_out, nullptr);

  (void)in_sizes; (void)n_in; (void)out_size; (void)ws_size;
}